// Round 14
// baseline (274.182 us; speedup 1.0000x reference)
//
#include <hip/hip_runtime.h>
#include <hip/hip_fp16.h>
#include <cstdint>
#include <cstddef>

typedef _Float16 f16;
typedef __attribute__((ext_vector_type(4))) _Float16 f16x4;
typedef __attribute__((ext_vector_type(8))) _Float16 f16x8;
typedef __attribute__((ext_vector_type(4))) float f32x4;

#define C_INV_SQRT2 0.70710678118654752440f

__device__ __forceinline__ void gld_lds16(const void* g, void* l) {
  __builtin_amdgcn_global_load_lds((const __attribute__((address_space(1))) void*)g,
                                   (__attribute__((address_space(3))) void*)l, 16, 0, 0);
}

// ---------------- conversion kernels ----------------
__global__ __launch_bounds__(256) void cvt_f32_f16_k(const float* __restrict__ in,
                                                     f16* __restrict__ out, int n4) {
  int i = blockIdx.x * 256 + threadIdx.x;
  if (i >= n4) return;
  const float4 x = ((const float4*)in)[i];
  f16x4 y;
  y.x = (f16)x.x; y.y = (f16)x.y; y.z = (f16)x.z; y.w = (f16)x.w;
  ((f16x4*)out)[i] = y;
}

// pack W_qkv rows {0..1023} and {2048..3071} into Wo[2048][1024] f16; same for bias
__global__ __launch_bounds__(256) void pack_wqv_k(const float* __restrict__ W,
                                                  const float* __restrict__ b,
                                                  f16* __restrict__ Wo,
                                                  float* __restrict__ bo) {
  int i = blockIdx.x * 256 + threadIdx.x;
  int n = i >> 8;
  int c = (i & 255) * 4;
  int sn = (n < 1024) ? n : (n + 1024);
  const float4 x = *(const float4*)(W + (size_t)sn * 1024 + c);
  f16x4 y; y.x = (f16)x.x; y.y = (f16)x.y; y.z = (f16)x.z; y.w = (f16)x.w;
  *(f16x4*)(Wo + (size_t)n * 1024 + c) = y;
  if (i < 2048) bo[i] = b[(i < 1024) ? i : (i + 1024)];
}

// -------- 3-level Haar forward + weighted product + inverse, 8 samples --------
__device__ __forceinline__ void haar_mid(const f16x8 q8, const f16x8 v8,
                                         float wq0, float wq1, float wq2,
                                         float wv0, float wv1, float wv2,
                                         float* a8) {
  const float c = C_INV_SQRT2;
  float q[8], v[8];
#pragma unroll
  for (int i = 0; i < 8; i++) { q[i] = (float)q8[i]; v[i] = (float)v8[i]; }
  float qa1[4], qd1[4], va1[4], vd1[4];
#pragma unroll
  for (int i = 0; i < 4; i++) {
    qd1[i] = (q[2 * i] - q[2 * i + 1]) * c;
    qa1[i] = (q[2 * i] + q[2 * i + 1]) * c;
    vd1[i] = (v[2 * i] - v[2 * i + 1]) * c;
    va1[i] = (v[2 * i] + v[2 * i + 1]) * c;
  }
  float qa2[2], qd2[2], va2[2], vd2[2];
#pragma unroll
  for (int j = 0; j < 2; j++) {
    qd2[j] = (qa1[2 * j] - qa1[2 * j + 1]) * c;
    qa2[j] = (qa1[2 * j] + qa1[2 * j + 1]) * c;
    vd2[j] = (va1[2 * j] - va1[2 * j + 1]) * c;
    va2[j] = (va1[2 * j] + va1[2 * j + 1]) * c;
  }
  const float qd3 = (qa2[0] - qa2[1]) * c, qa3 = (qa2[0] + qa2[1]) * c;
  const float vd3 = (va2[0] - va2[1]) * c, va3 = (va2[0] + va2[1]) * c;
  const float pa = (qa3 * wq0) * (va3 * wv0);
  const float pd3 = (qd3 * wq1) * (vd3 * wv1);
  float pd2[2], pd1[4];
#pragma unroll
  for (int j = 0; j < 2; j++) pd2[j] = (qd2[j] * wq2) * (vd2[j] * wv2);
#pragma unroll
  for (int i = 0; i < 4; i++) pd1[i] = qd1[i] * vd1[i];
  float s2[2], s1[4];
  s2[0] = (pa + pd3) * c;
  s2[1] = (pa - pd3) * c;
#pragma unroll
  for (int j = 0; j < 2; j++) {
    s1[2 * j] = (s2[j] + pd2[j]) * c;
    s1[2 * j + 1] = (s2[j] - pd2[j]) * c;
  }
#pragma unroll
  for (int i = 0; i < 4; i++) {
    a8[2 * i] = (s1[i] + pd1[i]) * c;
    a8[2 * i + 1] = (s1[i] - pd1[i]) * c;
  }
}

// ---- 256x256 GEMM, 8 waves (2M x 4N), m201 two-barrier phase, BK=32 x 4 buf ----
// C[M,N] = A[M,K]*B[N,K]^T + bias.  512 threads; per-wave output 128(M) x 64(N).
// LDS: 4 buf x {A,B} x [256 rows x 32 f16] = 128 KiB.  Stage-ahead-3 (R3 ledger):
//   stage(s+3) issued in ph0(s); at ph0(s) outstanding = {s,s+1,s+2} (12 loads)
//   -> vmcnt(8) certifies slice s (issued ~3 slices = ~5600 cyc ago -> free).
//   Tail: s=NS-2 -> vmcnt(4); s=NS-1 -> vmcnt(0).
// Per slice, TWO 16-MFMA phases (m201 pattern: staggered pre-barrier reads,
// clean post-barrier MFMA run):
//   ph0: vmcnt -> bar -> stage(s+3) -> read B(4)+A-lo(4) -> MFMA q0 (mi0..3)
//        -> PRE-BARRIER read A-hi(4)          [overlaps other waves' q0 tails]
//   ph1: bar -> lgkmcnt(0)+sched_barrier -> pure MFMA q1 (mi4..7, zero waits)
// Overwrite safety: all slice-(s-1) reads drained by ph1(s-1)'s lgkm(0), which
// precedes every wave's arrival at ph0(s)'s barrier; stage(s+3) (overwriting
// buf (s-1)&3) issues after that barrier -> race-free.
// LDS swizzle (R3-verified 0 conflicts): slot u -> (row=u>>2, chunk=(u&3)^((u>>3)&3));
//   read chunk' = chunk ^ ((row>>1)&3).  Both-sides (rule 21).
// T1 bijective XCD swizzle (nwg % 8 == 0).  T5 setprio around MFMA clusters.

#define STAGE4(bufi, k0)                          \
  {                                               \
    f16* LA = &lds[bufi][0][0];                   \
    f16* LB = &lds[bufi][1][0];                   \
    gld_lds16(pGA0 + (k0), LA + dst0);            \
    gld_lds16(pGA1 + (k0), LA + dst1);            \
    gld_lds16(pGB0 + (k0), LB + dst0);            \
    gld_lds16(pGB1 + (k0), LB + dst1);            \
  }

template <typename CT, bool FUSED>
__global__ __launch_bounds__(512, 2) void gemm256_k(const f16* __restrict__ A,
                                                    const f16* __restrict__ B,
                                                    const float* __restrict__ bias,
                                                    CT* __restrict__ C,
                                                    const float* __restrict__ wq,
                                                    const float* __restrict__ wv,
                                                    int M, int N, int K, int nbx) {
  __shared__ f16 lds[4][2][256 * 32];  // [buf][A/B][256r x 32 f16] = 128 KiB
  const int t = threadIdx.x;
  const int w = t >> 6, l = t & 63;
  const int wm = w >> 2, wn = w & 3;  // 2 x 4 wave grid
  const int hi = l >> 4, lo = l & 15;

  // T1: bijective XCD swizzle (nwg % 8 == 0)
  const int nwg = gridDim.x;
  const int cpx = nwg >> 3;
  const int bid = blockIdx.x;
  const int nid = (bid & 7) * cpx + (bid >> 3);
  const int by = nid / nbx, bx = nid - by * nbx;
  const int m0 = by * 256;
  const int n0 = bx * 256;   // non-fused col base
  const int d0 = bx * 128;   // fused dim base

  const f16* GA = A + (size_t)m0 * K;
  const f16* GBq = FUSED ? (B + (size_t)d0 * K) : (B + (size_t)n0 * K);
  const f16* GBv = FUSED ? (B + (size_t)(1024 + d0) * K) : (GBq + (size_t)128 * K);

  // staging: load i covers slot u = i*512 + t; row = u>>2 (i=0: 0..127,
  // i=1: 128..255), chunk = (t&3)^((t>>3)&3) (identical for both i).
  const int srow = t >> 2;                 // 0..127
  const int sch = (t & 3) ^ ((t >> 3) & 3);
  const f16* pGA0 = GA + (size_t)srow * K + sch * 8;
  const f16* pGA1 = GA + (size_t)(128 + srow) * K + sch * 8;
  const f16* pGB0 = GBq + (size_t)srow * K + sch * 8;
  const f16* pGB1 = GBv + (size_t)srow * K + sch * 8;  // == GBq+(128+srow)*K non-fused
  const int dst0 = (0 * 512 + w * 64) * 8;
  const int dst1 = (1 * 512 + w * 64) * 8;

  // read-side swizzled fragment offsets (f16 units within one [256][32] plane)
  int offA[8], offB[4];
#pragma unroll
  for (int mi = 0; mi < 8; mi++) {
    const int r = wm * 128 + mi * 16 + lo;
    offA[mi] = r * 32 + ((hi ^ ((r >> 1) & 3)) << 3);
  }
#pragma unroll
  for (int nj = 0; nj < 4; nj++) {
    const int r = wn * 64 + nj * 16 + lo;
    offB[nj] = r * 32 + ((hi ^ ((r >> 1) & 3)) << 3);
  }

  f32x4 acc[8][4] = {};
  const int NS = K >> 5;  // K=1024 -> 32

  STAGE4(0, 0);
  STAGE4(1, 32);
  STAGE4(2, 64);

  for (int s = 0; s < NS; ++s) {
    const int cur = s & 3;
    // ---- ph0: certify slice s; stage s+3; B + A-lo reads; MFMA q0
    if (s <= NS - 3) {
      asm volatile("s_waitcnt vmcnt(8)" ::: "memory");
    } else if (s == NS - 2) {
      asm volatile("s_waitcnt vmcnt(4)" ::: "memory");
    } else {
      asm volatile("s_waitcnt vmcnt(0)" ::: "memory");
    }
    __builtin_amdgcn_sched_barrier(0);
    __builtin_amdgcn_s_barrier();
    __builtin_amdgcn_sched_barrier(0);

    if (s + 3 < NS) STAGE4((s + 3) & 3, (s + 3) * 32);

    const f16* pA = &lds[cur][0][0];
    const f16* pB = &lds[cur][1][0];
    f16x8 bF[4], aLo[4], aHi[4];
#pragma unroll
    for (int nj = 0; nj < 4; nj++) bF[nj] = *(const f16x8*)(pB + offB[nj]);
#pragma unroll
    for (int mi = 0; mi < 4; mi++) aLo[mi] = *(const f16x8*)(pA + offA[mi]);
    __builtin_amdgcn_s_setprio(1);
#pragma unroll
    for (int mi = 0; mi < 4; mi++)
#pragma unroll
      for (int nj = 0; nj < 4; nj++)
        acc[mi][nj] =
            __builtin_amdgcn_mfma_f32_16x16x32_f16(aLo[mi], bF[nj], acc[mi][nj], 0, 0, 0);
    __builtin_amdgcn_s_setprio(0);
    // pre-barrier read-ahead: q1 frags (overlap other waves' q0 MFMA tails)
#pragma unroll
    for (int mi = 0; mi < 4; mi++) aHi[mi] = *(const f16x8*)(pA + offA[mi + 4]);
    __builtin_amdgcn_sched_barrier(0);

    // ---- ph1: clean MFMA run (reads already in flight; hard drain then go)
    __builtin_amdgcn_s_barrier();
    asm volatile("s_waitcnt lgkmcnt(0)" ::: "memory");
    __builtin_amdgcn_sched_barrier(0);
    __builtin_amdgcn_s_setprio(1);
#pragma unroll
    for (int mi = 0; mi < 4; mi++)
#pragma unroll
      for (int nj = 0; nj < 4; nj++)
        acc[mi + 4][nj] = __builtin_amdgcn_mfma_f32_16x16x32_f16(aHi[mi], bF[nj],
                                                                 acc[mi + 4][nj], 0, 0, 0);
    __builtin_amdgcn_s_setprio(0);
  }

  if (!FUSED) {
    // plain epilogue: C/D layout col = lane&15, row = (lane>>4)*4 + reg
#pragma unroll
    for (int mi = 0; mi < 8; mi++) {
#pragma unroll
      for (int nj = 0; nj < 4; nj++) {
        const int col = n0 + wn * 64 + nj * 16 + lo;
        const float bb = bias[col];
        const size_t base = (size_t)(m0 + wm * 128 + mi * 16 + hi * 4) * N + col;
#pragma unroll
        for (int r = 0; r < 4; r++) C[base + (size_t)r * N] = (CT)(acc[mi][nj][r] + bb);
      }
    }
  } else {
    // fused Haar-middle epilogue (R9-verified).
    char* ctb = (char*)&lds[0][0][0];  // 128 KiB c-tile, LDS dead now
    __builtin_amdgcn_s_barrier();      // all waves done with K-loop LDS
#pragma unroll
    for (int mi = 0; mi < 8; mi++) {
#pragma unroll
      for (int nj = 0; nj < 4; nj++) {
        const int col = wn * 64 + nj * 16 + lo;
        const int bidx = (col < 128) ? (d0 + col) : (1024 + d0 + col - 128);
        const float bb = bias[bidx];
        f16x4 y;
#pragma unroll
        for (int r = 0; r < 4; r++) y[r] = (f16)(acc[mi][nj][r] + bb);
        const int row2 = (wm * 128 + mi * 16 + hi * 4) * 2;
        const int byte = (col * 512 + row2) ^ ((col & 7) << 4);
        *(f16x4*)(ctb + byte) = y;
      }
    }
    asm volatile("s_waitcnt lgkmcnt(0)" ::: "memory");
    __builtin_amdgcn_s_barrier();
#pragma unroll 1
    for (int p = 0; p < 8; ++p) {
      const int c = t & 127;
      const int g = p * 4 + (t >> 7);
      const int byq = (c * 512 + g * 16) ^ ((c & 7) << 4);
      const f16x8 q8 = *(const f16x8*)(ctb + byq);
      const f16x8 v8 = *(const f16x8*)(ctb + byq + 65536);
      const int d = d0 + c;
      const int wb = (d >> 6) * 192 + (d & 63);
      float a8[8];
      haar_mid(q8, v8, wq[wb], wq[wb + 64], wq[wb + 128],
               wv[wb], wv[wb + 64], wv[wb + 128], a8);
      const size_t rb = (size_t)(m0 + g * 8) * 1024 + d;
#pragma unroll
      for (int i = 0; i < 8; i++) C[rb + (size_t)i * 1024] = (CT)a8[i];
    }
  }
}

// ---------------- standalone wavelet middle (ws-fallback path) ----------------
__global__ __launch_bounds__(256) void dwt_middle_k(const f16* __restrict__ qv,
                                                    const float* __restrict__ wq,
                                                    const float* __restrict__ wv,
                                                    f16* __restrict__ out) {
  const int g = blockIdx.x;
  const int d0 = threadIdx.x * 4;
  const size_t m0 = (size_t)g * 8;
  f16x4 qr[8], vr[8], o[8];
#pragma unroll
  for (int i = 0; i < 8; i++) {
    qr[i] = *(const f16x4*)(qv + (m0 + i) * 2048 + d0);
    vr[i] = *(const f16x4*)(qv + (m0 + i) * 2048 + 1024 + d0);
  }
#pragma unroll
  for (int dd = 0; dd < 4; dd++) {
    const int d = d0 + dd;
    const int wb = (d >> 6) * 192 + (d & 63);
    f16x8 q8, v8;
#pragma unroll
    for (int i = 0; i < 8; i++) { q8[i] = qr[i][dd]; v8[i] = vr[i][dd]; }
    float a8[8];
    haar_mid(q8, v8, wq[wb], wq[wb + 64], wq[wb + 128],
             wv[wb], wv[wb + 64], wv[wb + 128], a8);
#pragma unroll
    for (int i = 0; i < 8; i++) o[i][dd] = (f16)a8[i];
  }
#pragma unroll
  for (int i = 0; i < 8; i++) *(f16x4*)(out + (m0 + i) * 1024 + d0) = o[i];
}

// ---------------- launch ----------------
extern "C" void kernel_launch(void* const* d_in, const int* in_sizes, int n_in,
                              void* d_out, int out_size, void* d_ws, size_t ws_size,
                              hipStream_t stream) {
  (void)in_sizes; (void)n_in; (void)out_size;
  const float* query = (const float*)d_in[0];
  const float* W_qkv = (const float*)d_in[1];
  const float* b_qkv = (const float*)d_in[2];
  const float* W_out = (const float*)d_in[3];
  const float* b_out = (const float*)d_in[4];
  const float* wq = (const float*)d_in[5];
  const float* wv = (const float*)d_in[6];
  float* out = (float*)d_out;

  // workspace layout (R9-verified)
  char* ws = (char*)d_ws;
  f16* qf16 = (f16*)ws;                                // 67,108,864 B
  f16* Wqv = (f16*)(ws + 67108864);                    //  4,194,304 B
  float* bqv = (float*)(ws + 67108864 + 4194304);      //      8,192 B
  f16* Wout = (f16*)(ws + 67108864 + 4194304 + 8192);  //  2,097,152 B
  const size_t OFS_A = 67108864UL + 4194304 + 8192 + 2097152;  // 73,408,512
  const size_t NEED = OFS_A + 67108864UL;                      // 140,517,376

  cvt_f32_f16_k<<<dim3(8388608 / 256), dim3(256), 0, stream>>>(query, qf16, 8388608);
  pack_wqv_k<<<dim3(2048), dim3(256), 0, stream>>>(W_qkv, b_qkv, Wqv, bqv);
  cvt_f32_f16_k<<<dim3(262144 / 256), dim3(256), 0, stream>>>(W_out, Wout, 262144);

  if (ws_size >= NEED) {
    // fused path: GEMM1 + Haar middle in epilogue -> a in ws; no qv, no middle kernel
    f16* a_f16 = (f16*)(ws + OFS_A);
    gemm256_k<f16, true><<<dim3(8 * 128), dim3(512), 0, stream>>>(
        qf16, Wqv, bqv, a_f16, wq, wv, 32768, 1024, 1024, 8);
    gemm256_k<float, false><<<dim3(4 * 128), dim3(512), 0, stream>>>(
        a_f16, Wout, b_out, out, nullptr, nullptr, 32768, 1024, 1024, 4);
  } else {
    // fallback: qv in d_out, a aliases qf16
    f16* qv = (f16*)d_out;
    f16* a_f16 = qf16;
    gemm256_k<f16, false><<<dim3(8 * 128), dim3(512), 0, stream>>>(
        qf16, Wqv, bqv, qv, nullptr, nullptr, 32768, 2048, 1024, 8);
    dwt_middle_k<<<dim3(4096), dim3(256), 0, stream>>>(qv, wq, wv, a_f16);
    gemm256_k<float, false><<<dim3(4 * 128), dim3(512), 0, stream>>>(
        a_f16, Wout, b_out, out, nullptr, nullptr, 32768, 1024, 1024, 4);
  }
}

// Round 15
// 264.301 us; speedup vs baseline: 1.0374x; 1.0374x over previous
//
#include <hip/hip_runtime.h>
#include <hip/hip_fp16.h>
#include <cstdint>
#include <cstddef>

typedef _Float16 f16;
typedef __attribute__((ext_vector_type(4))) _Float16 f16x4;
typedef __attribute__((ext_vector_type(8))) _Float16 f16x8;
typedef __attribute__((ext_vector_type(4))) float f32x4;

#define C_INV_SQRT2 0.70710678118654752440f

__device__ __forceinline__ void gld_lds16(const void* g, void* l) {
  __builtin_amdgcn_global_load_lds((const __attribute__((address_space(1))) void*)g,
                                   (__attribute__((address_space(3))) void*)l, 16, 0, 0);
}

// ---------------- conversion kernels ----------------
__global__ __launch_bounds__(256) void cvt_f32_f16_k(const float* __restrict__ in,
                                                     f16* __restrict__ out, int n4) {
  int i = blockIdx.x * 256 + threadIdx.x;
  if (i >= n4) return;
  const float4 x = ((const float4*)in)[i];
  f16x4 y;
  y.x = (f16)x.x; y.y = (f16)x.y; y.z = (f16)x.z; y.w = (f16)x.w;
  ((f16x4*)out)[i] = y;
}

// pack W_qkv rows {0..1023} and {2048..3071} into Wo[2048][1024] f16; same for bias
__global__ __launch_bounds__(256) void pack_wqv_k(const float* __restrict__ W,
                                                  const float* __restrict__ b,
                                                  f16* __restrict__ Wo,
                                                  float* __restrict__ bo) {
  int i = blockIdx.x * 256 + threadIdx.x;
  int n = i >> 8;
  int c = (i & 255) * 4;
  int sn = (n < 1024) ? n : (n + 1024);
  const float4 x = *(const float4*)(W + (size_t)sn * 1024 + c);
  f16x4 y; y.x = (f16)x.x; y.y = (f16)x.y; y.z = (f16)x.z; y.w = (f16)x.w;
  *(f16x4*)(Wo + (size_t)n * 1024 + c) = y;
  if (i < 2048) bo[i] = b[(i < 1024) ? i : (i + 1024)];
}

// -------- 3-level Haar forward + weighted product + inverse, 8 samples --------
__device__ __forceinline__ void haar_mid(const f16x8 q8, const f16x8 v8,
                                         float wq0, float wq1, float wq2,
                                         float wv0, float wv1, float wv2,
                                         float* a8) {
  const float c = C_INV_SQRT2;
  float q[8], v[8];
#pragma unroll
  for (int i = 0; i < 8; i++) { q[i] = (float)q8[i]; v[i] = (float)v8[i]; }
  float qa1[4], qd1[4], va1[4], vd1[4];
#pragma unroll
  for (int i = 0; i < 4; i++) {
    qd1[i] = (q[2 * i] - q[2 * i + 1]) * c;
    qa1[i] = (q[2 * i] + q[2 * i + 1]) * c;
    vd1[i] = (v[2 * i] - v[2 * i + 1]) * c;
    va1[i] = (v[2 * i] + v[2 * i + 1]) * c;
  }
  float qa2[2], qd2[2], va2[2], vd2[2];
#pragma unroll
  for (int j = 0; j < 2; j++) {
    qd2[j] = (qa1[2 * j] - qa1[2 * j + 1]) * c;
    qa2[j] = (qa1[2 * j] + qa1[2 * j + 1]) * c;
    vd2[j] = (va1[2 * j] - va1[2 * j + 1]) * c;
    va2[j] = (va1[2 * j] + va1[2 * j + 1]) * c;
  }
  const float qd3 = (qa2[0] - qa2[1]) * c, qa3 = (qa2[0] + qa2[1]) * c;
  const float vd3 = (va2[0] - va2[1]) * c, va3 = (va2[0] + va2[1]) * c;
  const float pa = (qa3 * wq0) * (va3 * wv0);
  const float pd3 = (qd3 * wq1) * (vd3 * wv1);
  float pd2[2], pd1[4];
#pragma unroll
  for (int j = 0; j < 2; j++) pd2[j] = (qd2[j] * wq2) * (vd2[j] * wv2);
#pragma unroll
  for (int i = 0; i < 4; i++) pd1[i] = qd1[i] * vd1[i];
  float s2[2], s1[4];
  s2[0] = (pa + pd3) * c;
  s2[1] = (pa - pd3) * c;
#pragma unroll
  for (int j = 0; j < 2; j++) {
    s1[2 * j] = (s2[j] + pd2[j]) * c;
    s1[2 * j + 1] = (s2[j] - pd2[j]) * c;
  }
#pragma unroll
  for (int i = 0; i < 4; i++) {
    a8[2 * i] = (s1[i] + pd1[i]) * c;
    a8[2 * i + 1] = (s1[i] - pd1[i]) * c;
  }
}

// ---- 256x256 GEMM, 8 waves (2M x 4N), R8/R9 4-phase/K-tile schedule ----
// C[M,N] = A[M,K]*B[N,K]^T + bias.  512 threads; per-wave output 128(M) x 64(N).
// K-tile BK=64; LDS = 2 buf x {A,B} x 2 halves x [128 rows x 64 f16] = 128 KiB.
// STAGE SCHEDULE: Ah0,Ah1 of tile x @ (x-2).p2,p3 ; Bh0,Bh1 @ (x-1).p0,p1.
// PHASES of tile t (buf = t&1):
//  p0: vmcnt(4) [tile-t halves landed; A(t+1) = 4 loads stay in flight]
//      -> barrier -> reads: A mi0-3 (8) + B all (8) -> stage Bh0(t+1) -> 16 MFMA
//  p1: barrier -> reads A mi4-7 (8) -> stage Bh1(t+1) -> 16 MFMA
//  p2: lgkmcnt(0) [tile-t reads RETURNED] -> barrier -> stage Ah0(t+2) -> 16 MFMA
//  p3: lgkmcnt(0) -> barrier -> stage Ah1(t+2) -> 16 MFMA
// vmcnt ledger @ t.p0: outstanding <= {Ah(t+1):4} after drain -> vmcnt(4); last -> 0.
// LDS swizzle (both-sides): chunk' = chunk ^ (row & 7) on 16B chunks of 64-f16 rows.
// T1 bijective XCD swizzle (nwg % 8 == 0).  T5 setprio around MFMA clusters.
// [Plateau note: R3/R8/R9/R12/R13 schedule variants all measure 40±1% MfmaUtil;
//  this config is the best-measured total (263 µs, R9).]

#define STAGEH(bufi, mat, half, Gbase, k0)                         \
  {                                                                \
    f16* Ld = &lds[bufi][mat][half][0];                            \
    const f16* Gp = (Gbase) + (size_t)srow * K + (k0) + sch * 8;   \
    gld_lds16(Gp, Ld + (w * 64) * 8);                              \
    gld_lds16(Gp + (size_t)64 * K, Ld + (4096 + w * 64 * 8));      \
  }

#define MFMA_PH(mi0)                                                             \
  __builtin_amdgcn_s_setprio(1);                                                 \
  _Pragma("unroll") for (int mm = (mi0); mm < (mi0) + 2; mm++)                   \
      _Pragma("unroll") for (int nj = 0; nj < 4; nj++) {                         \
    acc[mm][nj] = __builtin_amdgcn_mfma_f32_16x16x32_f16(aF[mm][0], bF[nj][0],   \
                                                         acc[mm][nj], 0, 0, 0);  \
    acc[mm][nj] = __builtin_amdgcn_mfma_f32_16x16x32_f16(aF[mm][1], bF[nj][1],   \
                                                         acc[mm][nj], 0, 0, 0);  \
  }                                                                              \
  __builtin_amdgcn_s_setprio(0);

#define BAR_SEQ()                       \
  __builtin_amdgcn_sched_barrier(0);    \
  __builtin_amdgcn_s_barrier();         \
  __builtin_amdgcn_sched_barrier(0);

template <typename CT, bool FUSED>
__global__ __launch_bounds__(512, 2) void gemm256_k(const f16* __restrict__ A,
                                                    const f16* __restrict__ B,
                                                    const float* __restrict__ bias,
                                                    CT* __restrict__ C,
                                                    const float* __restrict__ wq,
                                                    const float* __restrict__ wv,
                                                    int M, int N, int K, int nbx) {
  __shared__ f16 lds[2][2][2][128 * 64];  // 128 KiB
  const int t = threadIdx.x;
  const int w = t >> 6, l = t & 63;
  const int wm = w >> 2, wn = w & 3;  // 2 x 4 wave grid
  const int hi = l >> 4, lo = l & 15;

  // T1: bijective XCD swizzle (nwg % 8 == 0)
  const int nwg = gridDim.x;
  const int cpx = nwg >> 3;
  const int bid = blockIdx.x;
  const int nid = (bid & 7) * cpx + (bid >> 3);
  const int by = nid / nbx, bx = nid - by * nbx;
  const int m0 = by * 256;
  const int n0 = bx * 256;   // non-fused col base
  const int d0 = bx * 128;   // fused dim base

  const f16* GA = A + (size_t)m0 * K;
  const f16* GBq = FUSED ? (B + (size_t)d0 * K) : (B + (size_t)n0 * K);
  const f16* GBv = FUSED ? (B + (size_t)(1024 + d0) * K) : (GBq + (size_t)128 * K);

  // staging: load i covers slot u = i*512 + t of 1024 slots per half-plane;
  // row = u>>3 (0..127), chunk = (u&7) ^ (row&7)  [inverse swizzle on source]
  const int srow = t >> 3;
  const int sch = (t & 7) ^ (srow & 7);

  // read-side per-lane swizzled column offsets (f16): chunk = kc*4+hi, ^ (lo&7)
  const int colk0 = ((hi ^ (lo & 7)) << 3);
  const int colk1 = (((4 | hi) ^ (lo & 7)) << 3);

  f32x4 acc[8][4] = {};
  f16x8 aF[8][2], bF[4][2];
  const int NT = K >> 6;  // K=1024 -> 16

  // prologue: A(0), B(0) into buf0; A(1) into buf1   (6 half-stages, 12 loads)
  STAGEH(0, 0, 0, GA, 0); STAGEH(0, 0, 1, GA + (size_t)128 * K, 0);
  STAGEH(0, 1, 0, GBq, 0); STAGEH(0, 1, 1, GBv, 0);
  STAGEH(1, 0, 0, GA, 64); STAGEH(1, 0, 1, GA + (size_t)128 * K, 64);

  for (int tt = 0; tt < NT; ++tt) {
    const int buf = tt & 1;
    const f16* pA = &lds[buf][0][wm][0] + lo * 64;
    const f16* pB = &lds[buf][1][wn >> 1][0] + (wn & 1) * 4096 + lo * 64;
    const f16* pA0 = pA + colk0;
    const f16* pA1 = pA + colk1;
    const f16* pB0 = pB + colk0;
    const f16* pB1 = pB + colk1;

    // ---------------- phase 0
    if (tt < NT - 1) {
      asm volatile("s_waitcnt vmcnt(4)" ::: "memory");
    } else {
      asm volatile("s_waitcnt vmcnt(0)" ::: "memory");
    }
    BAR_SEQ();
    aF[0][0] = *(const f16x8*)(pA0 + 0 * 1024);
    aF[0][1] = *(const f16x8*)(pA1 + 0 * 1024);
    aF[1][0] = *(const f16x8*)(pA0 + 1 * 1024);
    aF[1][1] = *(const f16x8*)(pA1 + 1 * 1024);
#pragma unroll
    for (int nj = 0; nj < 4; nj++) {
      bF[nj][0] = *(const f16x8*)(pB0 + nj * 1024);
      bF[nj][1] = *(const f16x8*)(pB1 + nj * 1024);
    }
    aF[2][0] = *(const f16x8*)(pA0 + 2 * 1024);
    aF[2][1] = *(const f16x8*)(pA1 + 2 * 1024);
    aF[3][0] = *(const f16x8*)(pA0 + 3 * 1024);
    aF[3][1] = *(const f16x8*)(pA1 + 3 * 1024);
    if (tt + 1 < NT) STAGEH(buf ^ 1, 1, 0, GBq, (tt + 1) * 64);
    MFMA_PH(0);

    // ---------------- phase 1
    BAR_SEQ();
#pragma unroll
    for (int mi = 4; mi < 8; mi++) {
      aF[mi][0] = *(const f16x8*)(pA0 + mi * 1024);
      aF[mi][1] = *(const f16x8*)(pA1 + mi * 1024);
    }
    if (tt + 1 < NT) STAGEH(buf ^ 1, 1, 1, GBv, (tt + 1) * 64);
    MFMA_PH(2);

    // ---------------- phase 2
    asm volatile("s_waitcnt lgkmcnt(0)" ::: "memory");
    BAR_SEQ();
    if (tt + 2 < NT) STAGEH(buf, 0, 0, GA, (tt + 2) * 64);
    MFMA_PH(4);

    // ---------------- phase 3
    asm volatile("s_waitcnt lgkmcnt(0)" ::: "memory");
    BAR_SEQ();
    if (tt + 2 < NT) STAGEH(buf, 0, 1, GA + (size_t)128 * K, (tt + 2) * 64);
    MFMA_PH(6);
  }

  if (!FUSED) {
    // plain epilogue: C/D layout col = lane&15, row = (lane>>4)*4 + reg
#pragma unroll
    for (int mi = 0; mi < 8; mi++) {
#pragma unroll
      for (int nj = 0; nj < 4; nj++) {
        const int col = n0 + wn * 64 + nj * 16 + lo;
        const float bb = bias[col];
        const size_t base = (size_t)(m0 + wm * 128 + mi * 16 + hi * 4) * N + col;
#pragma unroll
        for (int r = 0; r < 4; r++) C[base + (size_t)r * N] = (CT)(acc[mi][nj][r] + bb);
      }
    }
  } else {
    // fused Haar-middle epilogue (R9-verified).
    char* ctb = (char*)&lds[0][0][0][0];  // 128 KiB c-tile, LDS dead now
#pragma unroll
    for (int mi = 0; mi < 8; mi++) {
#pragma unroll
      for (int nj = 0; nj < 4; nj++) {
        const int col = wn * 64 + nj * 16 + lo;
        const int bidx = (col < 128) ? (d0 + col) : (1024 + d0 + col - 128);
        const float bb = bias[bidx];
        f16x4 y;
#pragma unroll
        for (int r = 0; r < 4; r++) y[r] = (f16)(acc[mi][nj][r] + bb);
        const int row2 = (wm * 128 + mi * 16 + hi * 4) * 2;
        const int byte = (col * 512 + row2) ^ ((col & 7) << 4);
        *(f16x4*)(ctb + byte) = y;
      }
    }
    asm volatile("s_waitcnt lgkmcnt(0)" ::: "memory");
    __builtin_amdgcn_s_barrier();
#pragma unroll 1
    for (int p = 0; p < 8; ++p) {
      const int c = t & 127;
      const int g = p * 4 + (t >> 7);
      const int byq = (c * 512 + g * 16) ^ ((c & 7) << 4);
      const f16x8 q8 = *(const f16x8*)(ctb + byq);
      const f16x8 v8 = *(const f16x8*)(ctb + byq + 65536);
      const int d = d0 + c;
      const int wb = (d >> 6) * 192 + (d & 63);
      float a8[8];
      haar_mid(q8, v8, wq[wb], wq[wb + 64], wq[wb + 128],
               wv[wb], wv[wb + 64], wv[wb + 128], a8);
      const size_t rb = (size_t)(m0 + g * 8) * 1024 + d;
#pragma unroll
      for (int i = 0; i < 8; i++) C[rb + (size_t)i * 1024] = (CT)a8[i];
    }
  }
}

// ---------------- standalone wavelet middle (ws-fallback path) ----------------
__global__ __launch_bounds__(256) void dwt_middle_k(const f16* __restrict__ qv,
                                                    const float* __restrict__ wq,
                                                    const float* __restrict__ wv,
                                                    f16* __restrict__ out) {
  const int g = blockIdx.x;
  const int d0 = threadIdx.x * 4;
  const size_t m0 = (size_t)g * 8;
  f16x4 qr[8], vr[8], o[8];
#pragma unroll
  for (int i = 0; i < 8; i++) {
    qr[i] = *(const f16x4*)(qv + (m0 + i) * 2048 + d0);
    vr[i] = *(const f16x4*)(qv + (m0 + i) * 2048 + 1024 + d0);
  }
#pragma unroll
  for (int dd = 0; dd < 4; dd++) {
    const int d = d0 + dd;
    const int wb = (d >> 6) * 192 + (d & 63);
    f16x8 q8, v8;
#pragma unroll
    for (int i = 0; i < 8; i++) { q8[i] = qr[i][dd]; v8[i] = vr[i][dd]; }
    float a8[8];
    haar_mid(q8, v8, wq[wb], wq[wb + 64], wq[wb + 128],
             wv[wb], wv[wb + 64], wv[wb + 128], a8);
#pragma unroll
    for (int i = 0; i < 8; i++) o[i][dd] = (f16)a8[i];
  }
#pragma unroll
  for (int i = 0; i < 8; i++) *(f16x4*)(out + (m0 + i) * 1024 + d0) = o[i];
}

// ---------------- launch ----------------
extern "C" void kernel_launch(void* const* d_in, const int* in_sizes, int n_in,
                              void* d_out, int out_size, void* d_ws, size_t ws_size,
                              hipStream_t stream) {
  (void)in_sizes; (void)n_in; (void)out_size;
  const float* query = (const float*)d_in[0];
  const float* W_qkv = (const float*)d_in[1];
  const float* b_qkv = (const float*)d_in[2];
  const float* W_out = (const float*)d_in[3];
  const float* b_out = (const float*)d_in[4];
  const float* wq = (const float*)d_in[5];
  const float* wv = (const float*)d_in[6];
  float* out = (float*)d_out;

  // workspace layout (R9-verified)
  char* ws = (char*)d_ws;
  f16* qf16 = (f16*)ws;                                // 67,108,864 B
  f16* Wqv = (f16*)(ws + 67108864);                    //  4,194,304 B
  float* bqv = (float*)(ws + 67108864 + 4194304);      //      8,192 B
  f16* Wout = (f16*)(ws + 67108864 + 4194304 + 8192);  //  2,097,152 B
  const size_t OFS_A = 67108864UL + 4194304 + 8192 + 2097152;  // 73,408,512
  const size_t NEED = OFS_A + 67108864UL;                      // 140,517,376

  cvt_f32_f16_k<<<dim3(8388608 / 256), dim3(256), 0, stream>>>(query, qf16, 8388608);
  pack_wqv_k<<<dim3(2048), dim3(256), 0, stream>>>(W_qkv, b_qkv, Wqv, bqv);
  cvt_f32_f16_k<<<dim3(262144 / 256), dim3(256), 0, stream>>>(W_out, Wout, 262144);

  if (ws_size >= NEED) {
    // fused path: GEMM1 + Haar middle in epilogue -> a in ws; no qv, no middle kernel
    f16* a_f16 = (f16*)(ws + OFS_A);
    gemm256_k<f16, true><<<dim3(8 * 128), dim3(512), 0, stream>>>(
        qf16, Wqv, bqv, a_f16, wq, wv, 32768, 1024, 1024, 8);
    gemm256_k<float, false><<<dim3(4 * 128), dim3(512), 0, stream>>>(
        a_f16, Wout, b_out, out, nullptr, nullptr, 32768, 1024, 1024, 4);
  } else {
    // fallback: qv in d_out, a aliases qf16
    f16* qv = (f16*)d_out;
    f16* a_f16 = qf16;
    gemm256_k<f16, false><<<dim3(8 * 128), dim3(512), 0, stream>>>(
        qf16, Wqv, bqv, qv, nullptr, nullptr, 32768, 2048, 1024, 8);
    dwt_middle_k<<<dim3(4096), dim3(256), 0, stream>>>(qv, wq, wv, a_f16);
    gemm256_k<float, false><<<dim3(4 * 128), dim3(512), 0, stream>>>(
        a_f16, Wout, b_out, out, nullptr, nullptr, 32768, 1024, 1024, 4);
  }
}